// Round 3
// baseline (4121.415 us; speedup 1.0000x reference)
//
#include <hip/hip_runtime.h>
#include <math.h>

#define N_ 32
#define C_ 64
#define T_ 128
#define V_ 25
#define K_ 10
#define VK_ (V_ * K_)          // 250
#define GRID_ 1024
#define ROUNDS_ 8              // 8192 quarter-slabs / 1024 blocks
#define QT_ 32                 // t-rows per quarter slab
#define QF_ (QT_ * VK_)        // 8000 floats per quarter
#define Q4_ (QF_ / 4)          // 2000 float4 per quarter

// Persistent fused kernel. Block b, round r handles quarter-slab s = r*1024+b:
//   n = s>>8, c = (s&255)>>2, q = s&3  (t-range [32q, 32q+32)).
// Every n-group (256 quarter-slabs) maps to one aligned 256-block chunk
// [g*256,(g+1)*256) in EVERY round, so a chunk only ever waits on itself;
// any >=256-block resident prefix makes progress -> no dispatch-order deadlock.
// Occupancy: 2KB LDS, <=128 VGPR (launch_bounds 256,4) -> whole grid resident.
__global__ __launch_bounds__(256, 4) void fused_kernel(
    const float* __restrict__ rf, const float* __restrict__ w1,
    const float* __restrict__ b1, const float* __restrict__ w2,
    const float* __restrict__ b2, float* __restrict__ out,
    float* __restrict__ g_logits, unsigned int* __restrict__ g_cnt) {
  __shared__ float as[VK_];    // per-quarter column sums
  __shared__ float a_s[VK_];   // final a[n,v,k] for this n
  const int b = blockIdx.x, tid = threadIdx.x;
  const float bias = b2[0];
  for (int r = 0; r < ROUNDS_; ++r) {
    const int s = r * GRID_ + b;
    const int n = s >> 8;
    const int c = (s & 255) >> 2;
    const int q = s & 3;
    const size_t qbase = (size_t)(n * C_ + c) * (T_ * VK_) + (size_t)q * QF_;

    if (tid < VK_) as[tid] = 0.f;
    __syncthreads();

    // Phase A: stream quarter (flat float4, fully coalesced), fold column sums.
    // 1000 floats == 4 rows, 1000 % 250 == 0 -> column of float4 j is (4j) mod 250.
    const float4* src4 = reinterpret_cast<const float4*>(rf + qbase);
    for (int j = tid; j < Q4_; j += 256) {
      float4 x = src4[j];
      int c0 = (4 * j) % VK_;
      int c1 = c0 + 1; if (c1 >= VK_) c1 -= VK_;
      int c2 = c0 + 2; if (c2 >= VK_) c2 -= VK_;
      int c3 = c0 + 3; if (c3 >= VK_) c3 -= VK_;
      atomicAdd(&as[c0], x.x);
      atomicAdd(&as[c1], x.y);
      atomicAdd(&as[c2], x.z);
      atomicAdd(&as[c3], x.w);
    }
    __syncthreads();

    // Contribute rank-1 logit term: logits[n,v,k,p] += (colsum/T) * w1[k,p,c]
    if (tid < VK_) {
      const int k = tid % K_;
      const float mfv = as[tid] * (1.0f / T_);
      const float* w1p = w1 + (size_t)k * (K_ * C_) + c;   // w1[k][p][c], step C_
      float* lp = g_logits + ((size_t)n * VK_ + tid) * K_;
      #pragma unroll
      for (int p = 0; p < K_; ++p)
        atomicAdd(&lp[p], mfv * w1p[(size_t)p * C_]);
    }
    __threadfence();          // release: my atomics visible device-wide
    __syncthreads();
    if (tid == 0) {
      atomicAdd(&g_cnt[n], 1u);
      while (atomicAdd(&g_cnt[n], 0u) < 256u) __builtin_amdgcn_s_sleep(16);
    }
    __syncthreads();
    __threadfence();          // acquire side

    // Redundant finish: softmax over p, fold w2 -> a_s (atomic reads = coherent)
    if (tid < VK_) {
      const int k = tid % K_;
      float* lp = g_logits + ((size_t)n * VK_ + tid) * K_;
      float lg[K_];
      #pragma unroll
      for (int p = 0; p < K_; ++p)
        lg[p] = atomicAdd(&lp[p], 0.0f) + b1[k * K_ + p];
      float m = lg[0];
      #pragma unroll
      for (int p = 1; p < K_; ++p) m = fmaxf(m, lg[p]);
      float se = 0.f, av = 0.f;
      #pragma unroll
      for (int p = 0; p < K_; ++p) {
        float e = __expf(lg[p] - m);
        se += e; av += e * w2[p];
      }
      a_s[tid] = av / se;
    }
    __syncthreads();

    // Phase C: re-read quarter (L2/L3-hot, no HBM), dot with a, write out.
    for (int idx = tid; idx < QT_ * V_ / 2; idx += 256) {   // 400 float2 pairs
      const int ltv0 = 2 * idx;
      const float4* p4 = reinterpret_cast<const float4*>(rf + qbase + (size_t)ltv0 * K_);
      float4 x0 = p4[0], x1 = p4[1], x2 = p4[2], x3 = p4[3], x4 = p4[4];
      const int gtv0 = q * (QT_ * V_) + ltv0;
      int v0 = gtv0 % V_;
      int v1 = v0 + 1; if (v1 >= V_) v1 -= V_;
      const float* a0 = &a_s[v0 * K_];
      const float* a1 = &a_s[v1 * K_];
      float o0 = bias
               + x0.x * a0[0] + x0.y * a0[1] + x0.z * a0[2] + x0.w * a0[3]
               + x1.x * a0[4] + x1.y * a0[5] + x1.z * a0[6] + x1.w * a0[7]
               + x2.x * a0[8] + x2.y * a0[9];
      float o1 = bias
               + x2.z * a1[0] + x2.w * a1[1]
               + x3.x * a1[2] + x3.y * a1[3] + x3.z * a1[4] + x3.w * a1[5]
               + x4.x * a1[6] + x4.y * a1[7] + x4.z * a1[8] + x4.w * a1[9];
      float2 o; o.x = o0; o.y = o1;
      const size_t obase = (size_t)(n * C_ + c) * (T_ * V_) + gtv0;
      reinterpret_cast<float2*>(out)[obase >> 1] = o;
    }
    __syncthreads();
  }
}

extern "C" void kernel_launch(void* const* d_in, const int* in_sizes, int n_in,
                              void* d_out, int out_size, void* d_ws, size_t ws_size,
                              hipStream_t stream) {
  const float* rf = (const float*)d_in[0];   // (N,C,T,V,K) fp32
  const float* w1 = (const float*)d_in[1];   // (K,K,C)
  const float* b1 = (const float*)d_in[2];   // (K,K)
  const float* w2 = (const float*)d_in[3];   // (K,)
  const float* b2 = (const float*)d_in[4];   // (1,)
  float* out = (float*)d_out;                // (N,C,T,V)

  float*        g_logits = (float*)d_ws;                       // N*VK*K = 80000 floats
  unsigned int* g_cnt    = (unsigned int*)((char*)d_ws + (size_t)N_ * VK_ * K_ * sizeof(float));

  hipMemsetAsync(g_logits, 0, (size_t)N_ * VK_ * K_ * sizeof(float), stream);
  hipMemsetAsync(g_cnt, 0, N_ * sizeof(unsigned int), stream);
  fused_kernel<<<GRID_, 256, 0, stream>>>(rf, w1, b1, w2, b2, out, g_logits, g_cnt);
}

// Round 4
// 453.673 us; speedup vs baseline: 9.0845x; 9.0845x over previous
//
#include <hip/hip_runtime.h>
#include <math.h>

#define N_ 32
#define C_ 64
#define T_ 128
#define V_ 25
#define K_ 10
#define VK_ 250                 // V*K
#define NC_ (N_ * C_)           // 2048 slabs
#define GRID_ 1024
#define SLABF_ (T_ * VK_)       // 32000 floats per (n,c) slab
#define SLAB4_ (SLABF_ / 4)     // 8000 float4

// Persistent fused kernel, grid = 1024 blocks x 256 threads.
// Block b owns slabs nc = 2b and 2b+1 (same n = b>>5 for both).
// Phase A: stream both slabs once (coalesced float4), column-mean -> g_mf
//          (agent-scope scalar stores, 2 MB total).
// Barrier 1 (single counter, 1024 arrivals, relaxed-load polling).
// Blocks 0..31: block n computes a[n,v,k] = sum_p softmax_p(<mf,w1>+b1)*w2[p]
//          from g_mf (agent-scope loads) -> g_a (agent-scope stores).
// Barrier 2. Phase C: re-read own slabs (L3-resident: rf = 250 MiB vs 256 MiB
// Infinity Cache, nothing else evicted it) and write out.
// Full-grid co-residency: 2 KB LDS, launch_bounds(256,4) -> 4 blocks/CU x 256
// CUs = 1024; R3's rendezvous kernel already proved this holds on the harness.
// NO contended RMW atomics anywhere except 1 arrival add per block per barrier.
__global__ __launch_bounds__(256, 4) void fused2(
    const float* __restrict__ rf, const float* __restrict__ w1,
    const float* __restrict__ b1, const float* __restrict__ w2,
    const float* __restrict__ b2, float* __restrict__ out,
    float* __restrict__ g_mf, float* __restrict__ g_a,
    unsigned int* __restrict__ g_cnt) {
  __shared__ float as[VK_];     // per-slab column sums
  __shared__ float a_s[VK_];    // a[n] for phase C
  const int b = blockIdx.x, tid = threadIdx.x;
  const int n = b >> 5;

  // ---- Phase A: column means of both slabs ----
  for (int s = 0; s < 2; ++s) {
    const int nc = 2 * b + s;
    if (tid < VK_) as[tid] = 0.f;
    __syncthreads();
    if (tid < VK_) {
      // 1000 floats == 4 rows; 1000 % 250 == 0 -> float4 j covers cols (4j..4j+3) mod 250
      const float4* rf4 = reinterpret_cast<const float4*>(rf) + (size_t)nc * SLAB4_ + tid;
      float4 acc = make_float4(0.f, 0.f, 0.f, 0.f);
      #pragma unroll 8
      for (int i = 0; i < 32; ++i) {
        float4 x = rf4[(size_t)i * VK_];
        acc.x += x.x; acc.y += x.y; acc.z += x.z; acc.w += x.w;
      }
      int c0 = (4 * tid) % VK_;
      int c1 = c0 + 1; if (c1 >= VK_) c1 -= VK_;
      int c2 = c0 + 2; if (c2 >= VK_) c2 -= VK_;
      int c3 = c0 + 3; if (c3 >= VK_) c3 -= VK_;
      atomicAdd(&as[c0], acc.x);   // LDS only, ~4-way, 1000 ops/block
      atomicAdd(&as[c1], acc.y);
      atomicAdd(&as[c2], acc.z);
      atomicAdd(&as[c3], acc.w);
    }
    __syncthreads();
    if (tid < VK_)
      __hip_atomic_store(&g_mf[(size_t)nc * VK_ + tid], as[tid] * (1.0f / T_),
                         __ATOMIC_RELAXED, __HIP_MEMORY_SCOPE_AGENT);
    __syncthreads();
  }

  // ---- Barrier 1 ----
  __syncthreads();
  if (tid == 0) {
    __threadfence();
    __hip_atomic_fetch_add(&g_cnt[0], 1u, __ATOMIC_ACQ_REL, __HIP_MEMORY_SCOPE_AGENT);
    while (__hip_atomic_load(&g_cnt[0], __ATOMIC_ACQUIRE, __HIP_MEMORY_SCOPE_AGENT) < GRID_)
      __builtin_amdgcn_s_sleep(16);
    __threadfence();
  }
  __syncthreads();

  // ---- a[n] computation: blocks 0..31, block index == n ----
  if (b < N_ && tid < VK_) {
    const int k = tid % K_;
    float lg[K_];
    #pragma unroll
    for (int p = 0; p < K_; ++p) lg[p] = b1[k * K_ + p];
    for (int c = 0; c < C_; ++c) {
      float m = __hip_atomic_load(&g_mf[((size_t)b * C_ + c) * VK_ + tid],
                                  __ATOMIC_RELAXED, __HIP_MEMORY_SCOPE_AGENT);
      const float* w1p = w1 + (size_t)k * (K_ * C_) + c;
      #pragma unroll
      for (int p = 0; p < K_; ++p) lg[p] += m * w1p[(size_t)p * C_];
    }
    float mx = lg[0];
    #pragma unroll
    for (int p = 1; p < K_; ++p) mx = fmaxf(mx, lg[p]);
    float se = 0.f, av = 0.f;
    #pragma unroll
    for (int p = 0; p < K_; ++p) {
      float e = __expf(lg[p] - mx);
      se += e; av += e * w2[p];
    }
    __hip_atomic_store(&g_a[(size_t)b * VK_ + tid], av / se,
                       __ATOMIC_RELAXED, __HIP_MEMORY_SCOPE_AGENT);
  }

  // ---- Barrier 2 ----
  __syncthreads();
  if (tid == 0) {
    __threadfence();
    __hip_atomic_fetch_add(&g_cnt[1], 1u, __ATOMIC_ACQ_REL, __HIP_MEMORY_SCOPE_AGENT);
    while (__hip_atomic_load(&g_cnt[1], __ATOMIC_ACQUIRE, __HIP_MEMORY_SCOPE_AGENT) < GRID_)
      __builtin_amdgcn_s_sleep(16);
    __threadfence();
  }
  __syncthreads();

  // stage a[n] to LDS
  if (tid < VK_)
    a_s[tid] = __hip_atomic_load(&g_a[(size_t)n * VK_ + tid],
                                 __ATOMIC_RELAXED, __HIP_MEMORY_SCOPE_AGENT);
  __syncthreads();

  // ---- Phase C: out[nc,t,v] = sum_k rf[nc,t,v,k]*a[n,v,k] + b2 ----
  const float bias = b2[0];
  for (int s = 0; s < 2; ++s) {
    const int nc = 2 * b + s;
    const float* slab = rf + (size_t)nc * SLABF_;
    for (int idx = tid; idx < T_ * V_ / 2; idx += 256) {   // 1600 float2 pairs
      const int tv0 = 2 * idx;
      const float4* p4 = reinterpret_cast<const float4*>(slab + (size_t)tv0 * K_);
      float4 x0 = p4[0], x1 = p4[1], x2 = p4[2], x3 = p4[3], x4 = p4[4];
      int v0 = tv0 % V_;
      int v1 = v0 + 1; if (v1 >= V_) v1 -= V_;
      const float* a0 = &a_s[v0 * K_];
      const float* a1 = &a_s[v1 * K_];
      float o0 = bias
               + x0.x * a0[0] + x0.y * a0[1] + x0.z * a0[2] + x0.w * a0[3]
               + x1.x * a0[4] + x1.y * a0[5] + x1.z * a0[6] + x1.w * a0[7]
               + x2.x * a0[8] + x2.y * a0[9];
      float o1 = bias
               + x2.z * a1[0] + x2.w * a1[1]
               + x3.x * a1[2] + x3.y * a1[3] + x3.z * a1[4] + x3.w * a1[5]
               + x4.x * a1[6] + x4.y * a1[7] + x4.z * a1[8] + x4.w * a1[9];
      float2 o; o.x = o0; o.y = o1;
      reinterpret_cast<float2*>(out)[((size_t)nc * (T_ * V_) + tv0) >> 1] = o;
    }
  }
}

extern "C" void kernel_launch(void* const* d_in, const int* in_sizes, int n_in,
                              void* d_out, int out_size, void* d_ws, size_t ws_size,
                              hipStream_t stream) {
  const float* rf = (const float*)d_in[0];   // (N,C,T,V,K) fp32
  const float* w1 = (const float*)d_in[1];   // (K,K,C)
  const float* b1 = (const float*)d_in[2];   // (K,K)
  const float* w2 = (const float*)d_in[3];   // (K,)
  const float* b2 = (const float*)d_in[4];   // (1,)
  float* out = (float*)d_out;                // (N,C,T,V)

  float*        g_mf  = (float*)d_ws;                                  // 2048*250 floats = 2 MB
  float*        g_a   = (float*)((char*)d_ws + (size_t)NC_ * VK_ * 4); // 32*250 floats
  unsigned int* g_cnt = (unsigned int*)((char*)d_ws + (size_t)NC_ * VK_ * 4 + (size_t)N_ * VK_ * 4);

  hipMemsetAsync(g_cnt, 0, 2 * sizeof(unsigned int), stream);
  fused2<<<GRID_, 256, 0, stream>>>(rf, w1, b1, w2, b2, out, g_mf, g_a, g_cnt);
}

// Round 5
// 216.270 us; speedup vs baseline: 19.0568x; 2.0977x over previous
//
#include <hip/hip_runtime.h>
#include <math.h>

#define N_ 32
#define C_ 64
#define T_ 128
#define V_ 25
#define K_ 10
#define VK_ 250                 // V*K
#define NC_ (N_ * C_)           // 2048 slabs
#define GRID_ 1024
#define SLABF_ (T_ * VK_)       // 32000 floats per (n,c) slab
#define SLAB4_ (SLABF_ / 4)     // 8000 float4
#define MFS_ 256                // padded row stride of g_mf (16B-aligned float4 rows)

// Persistent fused kernel, 1024 blocks x 256 threads (co-residency proven R3/R4).
// Block b owns slabs nc = 2b, 2b+1 (both of n = b>>5).
//  Phase A: stream both slabs once (float4, coalesced), column means -> g_mf
//           (plain float4 stores, padded stride).
//  ONE grid barrier: release fence (wbl2) + relaxed-poll counter + acquire
//           fence (inv). NO cache-op-per-poll (R4's 5x killer).
//  Phase B: EVERY block redundantly computes a[n,:] from g_mf (coalesced plain
//           loads, w1 in LDS) -- no second barrier, no idle blocks.
//  Phase C: re-read own slabs (LLC-resident) and write out.
__global__ __launch_bounds__(256, 4) void fused3(
    const float* __restrict__ rf, const float* __restrict__ w1,
    const float* __restrict__ b1, const float* __restrict__ w2,
    const float* __restrict__ b2, float* __restrict__ out,
    float* __restrict__ g_mf, unsigned int* __restrict__ g_cnt) {
  __shared__ float w1s[K_ * K_ * 65];   // [kp][c] stride 65 (bank-conflict break)
  __shared__ float b1s[K_ * K_];
  __shared__ float w2s[K_];
  __shared__ float as[VK_];
  __shared__ float a_s[VK_];
  const int b = blockIdx.x, tid = threadIdx.x;
  const int n = b >> 5;

  // stage weights to LDS
  for (int i = tid; i < K_ * K_ * C_; i += 256) w1s[(i >> 6) * 65 + (i & 63)] = w1[i];
  if (tid < K_ * K_) b1s[tid] = b1[tid];
  if (tid < K_)      w2s[tid] = w2[tid];

  // ---- Phase A: column means of both owned slabs ----
  for (int s = 0; s < 2; ++s) {
    const int nc = 2 * b + s;
    __syncthreads();
    if (tid < VK_) as[tid] = 0.f;
    __syncthreads();
    if (tid < VK_) {
      // 1000 floats == 4 rows; 1000 % 250 == 0 -> float4 j covers cols (4j..4j+3) mod 250
      const float4* rf4 = reinterpret_cast<const float4*>(rf) + (size_t)nc * SLAB4_ + tid;
      float4 acc = make_float4(0.f, 0.f, 0.f, 0.f);
      #pragma unroll 8
      for (int i = 0; i < 32; ++i) {
        float4 x = rf4[(size_t)i * VK_];
        acc.x += x.x; acc.y += x.y; acc.z += x.z; acc.w += x.w;
      }
      int c0 = (4 * tid) % VK_;
      int c1 = c0 + 1; if (c1 >= VK_) c1 -= VK_;
      int c2 = c0 + 2; if (c2 >= VK_) c2 -= VK_;
      int c3 = c0 + 3; if (c3 >= VK_) c3 -= VK_;
      atomicAdd(&as[c0], acc.x);   // LDS-only atomics
      atomicAdd(&as[c1], acc.y);
      atomicAdd(&as[c2], acc.z);
      atomicAdd(&as[c3], acc.w);
    }
    __syncthreads();
    // vectorized plain stores of the scaled means
    if (tid < 62) {
      float4 m4 = make_float4(as[4 * tid] * (1.f / T_), as[4 * tid + 1] * (1.f / T_),
                              as[4 * tid + 2] * (1.f / T_), as[4 * tid + 3] * (1.f / T_));
      *reinterpret_cast<float4*>(&g_mf[(size_t)nc * MFS_ + 4 * tid]) = m4;
    } else if (tid == 62) {
      float2 m2 = make_float2(as[248] * (1.f / T_), as[249] * (1.f / T_));
      *reinterpret_cast<float2*>(&g_mf[(size_t)nc * MFS_ + 248]) = m2;
    }
  }

  // ---- Single grid barrier (cheap cache ops: 2 fences per block TOTAL) ----
  __syncthreads();             // all stores issued & drained (vmcnt) per-wave
  if (tid == 0) {
    __threadfence();           // release: write back dirty L2 (wbl2) once
    __hip_atomic_fetch_add(&g_cnt[0], 1u, __ATOMIC_RELAXED, __HIP_MEMORY_SCOPE_AGENT);
    while (__hip_atomic_load(&g_cnt[0], __ATOMIC_RELAXED, __HIP_MEMORY_SCOPE_AGENT) < GRID_)
      __builtin_amdgcn_s_sleep(8);
    __threadfence();           // acquire: invalidate L1 + L2 once (kills stale lines)
  }
  __syncthreads();

  // ---- Phase B: redundant a[n] per block (coalesced plain loads of g_mf) ----
  if (tid < VK_) {
    const int k = tid % K_;
    float lg[K_];
    #pragma unroll
    for (int p = 0; p < K_; ++p) lg[p] = b1s[k * K_ + p];
    for (int c = 0; c < C_; ++c) {
      float m = g_mf[(size_t)(n * C_ + c) * MFS_ + tid];
      #pragma unroll
      for (int p = 0; p < K_; ++p) lg[p] += m * w1s[(k * K_ + p) * 65 + c];
    }
    float mx = lg[0];
    #pragma unroll
    for (int p = 1; p < K_; ++p) mx = fmaxf(mx, lg[p]);
    float se = 0.f, av = 0.f;
    #pragma unroll
    for (int p = 0; p < K_; ++p) {
      float e = __expf(lg[p] - mx);
      se += e; av += e * w2s[p];
    }
    a_s[tid] = av / se;
  }
  __syncthreads();

  // ---- Phase C: out[nc,t,v] = sum_k rf[nc,t,v,k]*a[n,v,k] + b2 ----
  const float bias = b2[0];
  for (int s = 0; s < 2; ++s) {
    const int nc = 2 * b + s;
    const float* slab = rf + (size_t)nc * SLABF_;
    for (int idx = tid; idx < T_ * V_ / 2; idx += 256) {   // 1600 float2 pairs
      const int tv0 = 2 * idx;
      const float4* p4 = reinterpret_cast<const float4*>(slab + (size_t)tv0 * K_);
      float4 x0 = p4[0], x1 = p4[1], x2 = p4[2], x3 = p4[3], x4 = p4[4];
      int v0 = tv0 % V_;
      int v1 = v0 + 1; if (v1 >= V_) v1 -= V_;
      const float* a0 = &a_s[v0 * K_];
      const float* a1 = &a_s[v1 * K_];
      float o0 = bias
               + x0.x * a0[0] + x0.y * a0[1] + x0.z * a0[2] + x0.w * a0[3]
               + x1.x * a0[4] + x1.y * a0[5] + x1.z * a0[6] + x1.w * a0[7]
               + x2.x * a0[8] + x2.y * a0[9];
      float o1 = bias
               + x2.z * a1[0] + x2.w * a1[1]
               + x3.x * a1[2] + x3.y * a1[3] + x3.z * a1[4] + x3.w * a1[5]
               + x4.x * a1[6] + x4.y * a1[7] + x4.z * a1[8] + x4.w * a1[9];
      float2 o; o.x = o0; o.y = o1;
      reinterpret_cast<float2*>(out)[((size_t)nc * (T_ * V_) + tv0) >> 1] = o;
    }
  }
}

extern "C" void kernel_launch(void* const* d_in, const int* in_sizes, int n_in,
                              void* d_out, int out_size, void* d_ws, size_t ws_size,
                              hipStream_t stream) {
  const float* rf = (const float*)d_in[0];   // (N,C,T,V,K) fp32
  const float* w1 = (const float*)d_in[1];   // (K,K,C)
  const float* b1 = (const float*)d_in[2];   // (K,K)
  const float* w2 = (const float*)d_in[3];   // (K,)
  const float* b2 = (const float*)d_in[4];   // (1,)
  float* out = (float*)d_out;                // (N,C,T,V)

  float*        g_mf  = (float*)d_ws;                                   // NC_*MFS_ floats = 2 MB
  unsigned int* g_cnt = (unsigned int*)((char*)d_ws + (size_t)NC_ * MFS_ * sizeof(float));

  hipMemsetAsync(g_cnt, 0, sizeof(unsigned int), stream);
  fused3<<<GRID_, 256, 0, stream>>>(rf, w1, b1, w2, b2, out, g_mf, g_cnt);
}

// Round 6
// 158.568 us; speedup vs baseline: 25.9915x; 1.3639x over previous
//
#include <hip/hip_runtime.h>
#include <math.h>

#define N_ 32
#define C_ 64
#define T_ 128
#define V_ 25
#define K_ 10
#define VK_ 250                 // V*K
#define NC_ (N_ * C_)           // 2048 slabs
#define GRID_ 1024
#define SLABF_ (T_ * VK_)       // 32000 floats per (n,c) slab
#define SLAB4_ (SLABF_ / 4)     // 8000 float4
#define MFS_ 256                // padded row stride of g_mf

// Persistent fused kernel, 1024 blocks x 256 threads (co-residency proven R3-R5).
// ZERO threadfences. All cross-block traffic (g_mf, counter) uses agent-scope
// RELAXED atomics -> sc1 ops that bypass per-XCD L2 and serialize at the
// coherent LLC. No wbl2/inv anywhere, so (a) no per-block fence cost (R5's
// killer), (b) rf lines cached in L2/LLC by Phase A survive for Phase C.
// Ordering: __syncthreads() before the arrival-add drains vmcnt for every
// wave (compiler emits s_waitcnt vmcnt(0) before s_barrier), so all sc1
// g_mf stores are at the LLC before the sc1 counter-add lands there.
__global__ __launch_bounds__(256, 4) void fused4(
    const float* __restrict__ rf, const float* __restrict__ w1,
    const float* __restrict__ b1, const float* __restrict__ w2,
    const float* __restrict__ b2, float* __restrict__ out,
    float* __restrict__ g_mf, unsigned int* __restrict__ g_cnt) {
  __shared__ float w1s[K_ * K_ * 65];   // [kp][c] stride 65
  __shared__ float b1s[K_ * K_];
  __shared__ float w2s[K_];
  __shared__ float as[VK_];
  __shared__ float a_s[VK_];
  const int b = blockIdx.x, tid = threadIdx.x;
  const int n = b >> 5;

  for (int i = tid; i < K_ * K_ * C_; i += 256) w1s[(i >> 6) * 65 + (i & 63)] = w1[i];
  if (tid < K_ * K_) b1s[tid] = b1[tid];
  if (tid < K_)      w2s[tid] = w2[tid];

  // ---- Phase A: column means of both owned slabs ----
  for (int s = 0; s < 2; ++s) {
    const int nc = 2 * b + s;
    __syncthreads();
    if (tid < VK_) as[tid] = 0.f;
    __syncthreads();
    if (tid < VK_) {
      // 1000 floats == 4 rows; 1000 % 250 == 0 -> float4 j covers cols (4j..4j+3) mod 250
      const float4* rf4 = reinterpret_cast<const float4*>(rf) + (size_t)nc * SLAB4_ + tid;
      float4 acc = make_float4(0.f, 0.f, 0.f, 0.f);
      #pragma unroll 8
      for (int i = 0; i < 32; ++i) {
        float4 x = rf4[(size_t)i * VK_];
        acc.x += x.x; acc.y += x.y; acc.z += x.z; acc.w += x.w;
      }
      int c0 = (4 * tid) % VK_;
      int c1 = c0 + 1; if (c1 >= VK_) c1 -= VK_;
      int c2 = c0 + 2; if (c2 >= VK_) c2 -= VK_;
      int c3 = c0 + 3; if (c3 >= VK_) c3 -= VK_;
      atomicAdd(&as[c0], acc.x);   // LDS-only atomics
      atomicAdd(&as[c1], acc.y);
      atomicAdd(&as[c2], acc.z);
      atomicAdd(&as[c3], acc.w);
    }
    __syncthreads();
    // sc1 (agent-scope relaxed) scalar stores: bypass L2, land at LLC, coalesced
    if (tid < VK_)
      __hip_atomic_store(&g_mf[(size_t)nc * MFS_ + tid], as[tid] * (1.0f / T_),
                         __ATOMIC_RELAXED, __HIP_MEMORY_SCOPE_AGENT);
  }

  // ---- Single grid barrier, fence-free ----
  __syncthreads();             // drains vmcnt of ALL waves' sc1 stores
  if (tid == 0) {
    __hip_atomic_fetch_add(&g_cnt[0], 1u, __ATOMIC_RELAXED, __HIP_MEMORY_SCOPE_AGENT);
    while (__hip_atomic_load(&g_cnt[0], __ATOMIC_RELAXED, __HIP_MEMORY_SCOPE_AGENT) < GRID_)
      __builtin_amdgcn_s_sleep(2);
  }
  __syncthreads();

  // ---- Phase B: redundant a[n] per block (sc1 coalesced loads of g_mf) ----
  if (tid < VK_) {
    const int k = tid % K_;
    float lg[K_];
    #pragma unroll
    for (int p = 0; p < K_; ++p) lg[p] = b1s[k * K_ + p];
    for (int c = 0; c < C_; ++c) {
      float m = __hip_atomic_load(&g_mf[(size_t)(n * C_ + c) * MFS_ + tid],
                                  __ATOMIC_RELAXED, __HIP_MEMORY_SCOPE_AGENT);
      #pragma unroll
      for (int p = 0; p < K_; ++p) lg[p] += m * w1s[(k * K_ + p) * 65 + c];
    }
    float mx = lg[0];
    #pragma unroll
    for (int p = 1; p < K_; ++p) mx = fmaxf(mx, lg[p]);
    float se = 0.f, av = 0.f;
    #pragma unroll
    for (int p = 0; p < K_; ++p) {
      float e = __expf(lg[p] - mx);
      se += e; av += e * w2s[p];
    }
    a_s[tid] = av / se;
  }
  __syncthreads();

  // ---- Phase C: out[nc,t,v] = sum_k rf[nc,t,v,k]*a[n,v,k] + b2 ----
  const float bias = b2[0];
  for (int s = 0; s < 2; ++s) {
    const int nc = 2 * b + s;
    const float* slab = rf + (size_t)nc * SLABF_;
    for (int idx = tid; idx < T_ * V_ / 2; idx += 256) {   // 1600 float2 pairs
      const int tv0 = 2 * idx;
      const float4* p4 = reinterpret_cast<const float4*>(slab + (size_t)tv0 * K_);
      float4 x0 = p4[0], x1 = p4[1], x2 = p4[2], x3 = p4[3], x4 = p4[4];
      int v0 = tv0 % V_;
      int v1 = v0 + 1; if (v1 >= V_) v1 -= V_;
      const float* a0 = &a_s[v0 * K_];
      const float* a1 = &a_s[v1 * K_];
      float o0 = bias
               + x0.x * a0[0] + x0.y * a0[1] + x0.z * a0[2] + x0.w * a0[3]
               + x1.x * a0[4] + x1.y * a0[5] + x1.z * a0[6] + x1.w * a0[7]
               + x2.x * a0[8] + x2.y * a0[9];
      float o1 = bias
               + x2.z * a1[0] + x2.w * a1[1]
               + x3.x * a1[2] + x3.y * a1[3] + x3.z * a1[4] + x3.w * a1[5]
               + x4.x * a1[6] + x4.y * a1[7] + x4.z * a1[8] + x4.w * a1[9];
      float2 o; o.x = o0; o.y = o1;
      reinterpret_cast<float2*>(out)[((size_t)nc * (T_ * V_) + tv0) >> 1] = o;
    }
  }
}

extern "C" void kernel_launch(void* const* d_in, const int* in_sizes, int n_in,
                              void* d_out, int out_size, void* d_ws, size_t ws_size,
                              hipStream_t stream) {
  const float* rf = (const float*)d_in[0];   // (N,C,T,V,K) fp32
  const float* w1 = (const float*)d_in[1];   // (K,K,C)
  const float* b1 = (const float*)d_in[2];   // (K,K)
  const float* w2 = (const float*)d_in[3];   // (K,)
  const float* b2 = (const float*)d_in[4];   // (1,)
  float* out = (float*)d_out;                // (N,C,T,V)

  float*        g_mf  = (float*)d_ws;                                   // NC_*MFS_ floats = 2 MB
  unsigned int* g_cnt = (unsigned int*)((char*)d_ws + (size_t)NC_ * MFS_ * sizeof(float));

  hipMemsetAsync(g_cnt, 0, sizeof(unsigned int), stream);
  fused4<<<GRID_, 256, 0, stream>>>(rf, w1, b1, w2, b2, out, g_mf, g_cnt);
}

// Round 8
// 92.334 us; speedup vs baseline: 44.6362x; 1.7173x over previous
//
#include <hip/hip_runtime.h>
#include <math.h>

#define N_ 32
#define C_ 64
#define T_ 128
#define V_ 25
#define K_ 10

typedef float vfloat2 __attribute__((ext_vector_type(2)));

// V*K = 250 floats per (n,c,t) row; slab per (n,c) = T*250 = 32000 floats = 8000 float4
// 1000 floats (= 4 rows) == 250 float4, and 1000 % 250 == 0, so a float4 at flat
// offset 4j + 1000*i always covers columns (4j..4j+3) mod 250 regardless of i.

// Kernel 1: mf[n,c,v,k] = (1/T) * sum_t rf[n,c,t,v,k]
// Flat float4 streaming (16 B/lane, 1 KiB/wave contiguous), column sums folded
// via LDS f32 atomics (max ~4-way contention).
__global__ __launch_bounds__(256) void mean_kernel(const float* __restrict__ rf,
                                                   float* __restrict__ mf) {
    __shared__ float as[V_ * K_];
    const int nc = blockIdx.x;          // 0..N*C-1
    const int j  = threadIdx.x;         // float4 lane within the 1000-float group
    if (j < V_ * K_) as[j] = 0.f;
    __syncthreads();
    if (j < 250) {
        const float4* rf4 = reinterpret_cast<const float4*>(rf) + (size_t)nc * 8000 + j;
        float4 s = make_float4(0.f, 0.f, 0.f, 0.f);
        #pragma unroll 8
        for (int i = 0; i < 32; ++i) {      // 32 groups of 4 rows
            float4 x = rf4[(size_t)i * 250];
            s.x += x.x; s.y += x.y; s.z += x.z; s.w += x.w;
        }
        const int c0 = (4 * j) % 250;       // even, <= 248
        atomicAdd(&as[c0], s.x);
        atomicAdd(&as[(c0 + 1) % 250], s.y);
        atomicAdd(&as[(c0 + 2) % 250], s.z);
        atomicAdd(&as[(c0 + 3) % 250], s.w);
    }
    __syncthreads();
    if (j < 125) {
        float2 o;
        o.x = as[2 * j]     * (1.0f / T_);
        o.y = as[2 * j + 1] * (1.0f / T_);
        reinterpret_cast<float2*>(mf)[(size_t)nc * 125 + j] = o;
    }
}

// Kernel 2: a[n,v,k] = sum_p softmax_p( sum_c mf[n,c,v,k]*w1[k,p,c] + b1[k,p] ) * w2[p]
// One block per n; thread = (v,k) pair (250 active of 256). mf loads are
// lane-coalesced (consecutive vk). w1 staged in LDS, stride 65 to break bank aliasing.
__global__ __launch_bounds__(256) void attn_kernel(const float* __restrict__ mf,
                                                   const float* __restrict__ w1,
                                                   const float* __restrict__ b1,
                                                   const float* __restrict__ w2,
                                                   float* __restrict__ a_out) {
    __shared__ float w1s[K_ * K_ * 65];   // [kp][c] stride 65
    __shared__ float b1s[K_ * K_];
    __shared__ float w2s[K_];
    const int n   = blockIdx.x;
    const int tid = threadIdx.x;
    for (int i = tid; i < K_ * K_ * C_; i += 256) {
        int kp = i >> 6;          // /64
        int c  = i & 63;
        w1s[kp * 65 + c] = w1[i];
    }
    if (tid < K_ * K_) b1s[tid] = b1[tid];
    if (tid < K_)      w2s[tid] = w2[tid];
    __syncthreads();
    if (tid >= V_ * K_) return;
    const int k = tid % K_;
    float mfv[C_];
    const float* mfp = mf + (size_t)n * C_ * (V_ * K_) + tid;
    #pragma unroll
    for (int c = 0; c < C_; ++c) mfv[c] = mfp[(size_t)c * (V_ * K_)];
    float lg[K_];
    #pragma unroll
    for (int p = 0; p < K_; ++p) {
        float s = b1s[k * K_ + p];
        const float* wrow = &w1s[(k * K_ + p) * 65];
        #pragma unroll
        for (int c = 0; c < C_; ++c) s += mfv[c] * wrow[c];
        lg[p] = s;
    }
    float m = lg[0];
    #pragma unroll
    for (int p = 1; p < K_; ++p) m = fmaxf(m, lg[p]);
    float se = 0.f, av = 0.f;
    #pragma unroll
    for (int p = 0; p < K_; ++p) {
        float e = __expf(lg[p] - m);
        se += e;
        av += e * w2s[p];
    }
    a_out[(size_t)n * (V_ * K_) + tid] = av / se;
}

// Kernel 3: out[n,c,t,v] = sum_k rf[n,c,t,v,k] * a[n,v,k] + b2
// Each block: one (n,c, chunk-of-640-tv). Each thread: 2 consecutive tv
// (20 floats = 5 aligned float4). a[n] (250 floats) staged in LDS.
// Output written with nontemporal stores (no reuse; keep L2/LLC for rf).
__global__ __launch_bounds__(320) void out_kernel(const float* __restrict__ rf,
                                                  const float* __restrict__ a,
                                                  const float* __restrict__ b2,
                                                  float* __restrict__ out) {
    __shared__ float as[V_ * K_];
    const int b     = blockIdx.x;
    const int chunk = b % 5;
    const int nc    = b / 5;
    const int n     = nc / C_;
    if (threadIdx.x < V_ * K_) as[threadIdx.x] = a[(size_t)n * (V_ * K_) + threadIdx.x];
    __syncthreads();
    const float bias = b2[0];
    const int tv0 = chunk * 640 + threadIdx.x * 2;      // even
    const size_t obase = (size_t)nc * (T_ * V_) + tv0;  // even
    const float4* p = reinterpret_cast<const float4*>(rf + obase * K_);
    float4 x0 = p[0], x1 = p[1], x2 = p[2], x3 = p[3], x4 = p[4];
    const int v0 = tv0 % V_;
    const int v1 = (tv0 + 1) % V_;
    const float* a0 = &as[v0 * K_];
    const float* a1 = &as[v1 * K_];
    float o0 = bias
             + x0.x * a0[0] + x0.y * a0[1] + x0.z * a0[2] + x0.w * a0[3]
             + x1.x * a0[4] + x1.y * a0[5] + x1.z * a0[6] + x1.w * a0[7]
             + x2.x * a0[8] + x2.y * a0[9];
    float o1 = bias
             + x2.z * a1[0] + x2.w * a1[1]
             + x3.x * a1[2] + x3.y * a1[3] + x3.z * a1[4] + x3.w * a1[5]
             + x4.x * a1[6] + x4.y * a1[7] + x4.z * a1[8] + x4.w * a1[9];
    vfloat2 o;
    o.x = o0;
    o.y = o1;
    __builtin_nontemporal_store(o, reinterpret_cast<vfloat2*>(out) + (obase >> 1));
}

extern "C" void kernel_launch(void* const* d_in, const int* in_sizes, int n_in,
                              void* d_out, int out_size, void* d_ws, size_t ws_size,
                              hipStream_t stream) {
    const float* rf = (const float*)d_in[0];   // (N,C,T,V,K) fp32
    const float* w1 = (const float*)d_in[1];   // (K,K,C)
    const float* b1 = (const float*)d_in[2];   // (K,K)
    const float* w2 = (const float*)d_in[3];   // (K,)
    const float* b2 = (const float*)d_in[4];   // (1,)
    float* out = (float*)d_out;                // (N,C,T,V)

    float* mf   = (float*)d_ws;                // N*C*V*K = 512000 floats
    float* a_vk = (float*)((char*)d_ws + (size_t)N_ * C_ * V_ * K_ * sizeof(float)); // 8000 floats

    mean_kernel<<<N_ * C_, 256, 0, stream>>>(rf, mf);
    attn_kernel<<<N_, 256, 0, stream>>>(mf, w1, b1, w2, a_vk);
    out_kernel<<<N_ * C_ * 5, 320, 0, stream>>>(rf, a_vk, b2, out);
}